// Round 9
// baseline (2447.443 us; speedup 1.0000x reference)
//
#include <hip/hip_runtime.h>

// PointNet++ SA module: FPS -> ball query (K nearest within R) -> gather ->
// 3-layer MLP -> masked max aggregation.
//
// B=4 batches, NP=8192 pts, MP=2048 centers/batch, K=64, R=0.2, D_IN=32.
// d_out = [x_out (8192*128) | pos_out (8192*3) | batch_out (8192)] as fp32.
//
// ws layout (bytes):
//   P1    : 0       .. 8388608  (32768 x 64 fp32) = x @ W1[0:32]
//   W2T   : 8388608 .. 8404992  (64x64 fp32, transposed)
//   flags : 8404992 .. 8405024  (prog[4], ticket, p1done)
//
// Round-9: fence-free producer/consumer handshake.  r8's overlap worked but
// its agent-scope release/acquire fences compiled to buffer_wbl2/buffer_inv
// (full per-XCD L2 writeback/invalidate) per publish/pickup — 8192 L2 wipes
// (FETCH 2.3->60MB) ate the entire overlap gain.  Now the ONLY cross-block
// data in the hot loop (pout coords + prog flags) uses relaxed agent-scope
// atomics (sc0/sc1: bypass non-coherent L2s, served at the LLC coherence
// point).  Producer orders coord-stores before the flag with a raw
// s_waitcnt vmcnt(0) (no cache maintenance); consumer polls + reads coords
// uncached with NO fence.  P1's one-time handshake keeps its fences.

#define BATCH 4
#define NP 8192
#define MP 2048
#define KNN 64
#define DIN 32
#define NWORK 200
#define NBLK (BATCH + NWORK)
#define CAND_CAP 512   // max real candidate count ~360 (measured r2-r8)

// One v_max_f32 + DPP step (r2-verified: plain fmaxf; asm variants regressed).
#define DPP_FMAX(v, ctrl)                                                     \
  {                                                                           \
    int _t = __builtin_amdgcn_update_dpp(__float_as_int(v),                   \
                                         __float_as_int(v), (ctrl), 0xF,      \
                                         0xF, false);                         \
    (v) = fmaxf((v), __int_as_float(_t));                                     \
  }

// One v_min_u32 + DPP step (integer: no canonicalization exists).
#define DPP_MINU(v, ctrl)                                                     \
  {                                                                           \
    unsigned _t = (unsigned)__builtin_amdgcn_update_dpp((int)(v), (int)(v),   \
                                                        (ctrl), 0xF, 0xF,    \
                                                        false);               \
    (v) = ((v) < _t) ? (v) : _t;                                              \
  }

#define DPP_WAVEMAX6(v)                                                       \
  {                                                                           \
    DPP_FMAX(v, 0x111); DPP_FMAX(v, 0x112); DPP_FMAX(v, 0x114);               \
    DPP_FMAX(v, 0x118); DPP_FMAX(v, 0x142); DPP_FMAX(v, 0x143);               \
  }

#define DPP_WAVEMINU6(v)                                                      \
  {                                                                           \
    DPP_MINU(v, 0x111); DPP_MINU(v, 0x112); DPP_MINU(v, 0x114);               \
    DPP_MINU(v, 0x118); DPP_MINU(v, 0x142); DPP_MINU(v, 0x143);               \
  }

typedef float v2f __attribute__((ext_vector_type(2)));

// Relaxed agent-scope atomics: compile to sc0/sc1 (bypass the non-coherent
// per-XCD L2s; served at the LLC coherence point).  NO fences attached.
__device__ __forceinline__ int aload(const int* p) {
  return __hip_atomic_load(p, __ATOMIC_RELAXED, __HIP_MEMORY_SCOPE_AGENT);
}
__device__ __forceinline__ void astore_i(int* p, int v) {
  __hip_atomic_store(p, v, __ATOMIC_RELAXED, __HIP_MEMORY_SCOPE_AGENT);
}
__device__ __forceinline__ float afload(const float* p) {
  return __hip_atomic_load(p, __ATOMIC_RELAXED, __HIP_MEMORY_SCOPE_AGENT);
}
__device__ __forceinline__ void afstore(float* p, float v) {
  __hip_atomic_store(p, v, __ATOMIC_RELAXED, __HIP_MEMORY_SCOPE_AGENT);
}

// ---------------------------------------------------------------- init -----
__global__ void init_k(int* __restrict__ flags) {
  if (threadIdx.x < 8) flags[threadIdx.x] = 0;
}

// ---------------------------------------------------------------- mega -----
__global__ __launch_bounds__(1024) void mega_k(const float* __restrict__ pos,
                                               const float* __restrict__ x,
                                               const float* __restrict__ W1,
                                               const float* __restrict__ b1,
                                               const float* __restrict__ W2,
                                               const float* __restrict__ b2,
                                               const float* __restrict__ W3,
                                               const float* __restrict__ b3,
                                               float* __restrict__ pout,
                                               float* __restrict__ bout,
                                               float* __restrict__ P1,
                                               float* __restrict__ W2T,
                                               float* __restrict__ xout,
                                               int* __restrict__ flags)
{
  // 98304B table (fps: ptab; workers: 16 x 512 u64 cand regions) + fps slots
  __shared__ __align__(16) float smem[NP * 3];
  __shared__ unsigned long long slt[2][16];

  int* const prog   = flags;        // prog[b] = published rows (i+1)
  int* const ticket = flags + 4;
  int* const p1done = flags + 5;

  const int bid = blockIdx.x;
  const int tid = threadIdx.x;
  const int lane = tid & 63, wid = tid >> 6;

  if (bid < BATCH) {
    // ===================== FPS (r2/r6-verified, 16 waves) =================
    const int b = bid;
    float* const ptab = smem;
    const float* __restrict__ pb = pos + (size_t)b * NP * 3;
    const int base = tid * 8;

    bout[b * MP + tid] = (float)b;
    bout[b * MP + 1024 + tid] = (float)b;

    // load 8 points; stage into LDS table; unpack to registers
    float t[24];
    const float4* __restrict__ pv = (const float4*)(pb + (size_t)tid * 24);
#pragma unroll
    for (int q = 0; q < 6; q++) *(float4*)&t[q * 4] = pv[q];
#pragma unroll
    for (int q = 0; q < 6; q++)
      *(float4*)&ptab[tid * 24 + q * 4] = *(float4*)&t[q * 4];

    v2f px[4], py[4], pz[4], d[4];
#pragma unroll
    for (int j = 0; j < 4; j++) {
      px[j].x = t[6 * j + 0]; py[j].x = t[6 * j + 1]; pz[j].x = t[6 * j + 2];
      px[j].y = t[6 * j + 3]; py[j].y = t[6 * j + 4]; pz[j].y = t[6 * j + 5];
    }

    const float c0x = pb[0], c0y = pb[1], c0z = pb[2];
    if (tid == 0) {  // sel[0] = 0   (uncached: workers read pout via LLC)
      afstore(&pout[(size_t)b * MP * 3 + 0], c0x);
      afstore(&pout[(size_t)b * MP * 3 + 1], c0y);
      afstore(&pout[(size_t)b * MP * 3 + 2], c0z);
    }

    float bv = -1.f;
    {
      v2f cx = {c0x, c0x}, cy = {c0y, c0y}, cz = {c0z, c0z};
#pragma unroll
      for (int j = 0; j < 4; j++) {
        v2f dx = px[j] - cx, dy = py[j] - cy, dz = pz[j] - cz;
        v2f nd = dx * dx + dy * dy + dz * dz;
        d[j] = nd;
        bv = fmaxf(bv, fmaxf(nd.x, nd.y));
      }
    }

    for (int i = 1; i < MP; i++) {
      float v = bv;
      DPP_WAVEMAX6(v);
      const float wmax =
          __int_as_float(__builtin_amdgcn_readlane(__float_as_int(v), 63));

      const unsigned long long m = __ballot(bv == wmax);
      const int src = (int)__builtin_ctzll(m);
      const int p = i & 1;
      if (lane == src) {
        int ks = 7;
#pragma unroll
        for (int k = 6; k >= 0; k--) {
          float dv = (k & 1) ? d[k >> 1].y : d[k >> 1].x;
          if (dv == wmax) ks = k;
        }
        slt[p][wid] = ((unsigned long long)__float_as_uint(wmax) << 32)
                      | (unsigned)(base + ks);
      }
      __syncthreads();

      const unsigned long long kv = slt[p][lane & 15];
      const float v2 = __uint_as_float((unsigned)(kv >> 32));
      float v2r = v2;
      DPP_FMAX(v2r, 0x111);
      DPP_FMAX(v2r, 0x112);
      DPP_FMAX(v2r, 0x114);
      DPP_FMAX(v2r, 0x118);
      const float mv =
          __int_as_float(__builtin_amdgcn_readlane(__float_as_int(v2r), 15));
      const unsigned long long m2 = __ballot(v2 == mv);
      const int mw = (int)__builtin_ctzll(m2);
      const int js = __builtin_amdgcn_readlane((int)(unsigned)kv, mw);
      const float ncx = ptab[js * 3 + 0];
      const float ncy = ptab[js * 3 + 1];
      const float ncz = ptab[js * 3 + 2];

      if (tid == 0) {
        // uncached coord stores: fire-and-forget to the LLC
        afstore(&pout[((size_t)b * MP + i) * 3 + 0], ncx);
        afstore(&pout[((size_t)b * MP + i) * 3 + 1], ncy);
        afstore(&pout[((size_t)b * MP + i) * 3 + 2], ncz);
        if ((i & 15) == 15) {
          // all prior coord stores have reached the coherence point; then
          // publish.  NO cache maintenance (this is the r8 bug fixed).
          asm volatile("s_waitcnt vmcnt(0)" ::: "memory");
          astore_i(&prog[b], i + 1);
        }
      }

      const v2f cx = {ncx, ncx}, cy = {ncy, ncy}, cz = {ncz, ncz};
      bv = -1.f;
#pragma unroll
      for (int j = 0; j < 4; j++) {
        v2f dx = px[j] - cx, dy = py[j] - cy, dz = pz[j] - cz;
        v2f nd = dx * dx + dy * dy + dz * dz;
        v2f dn;
        dn.x = fminf(d[j].x, nd.x);
        dn.y = fminf(d[j].y, nd.y);
        d[j] = dn;
        bv = fmaxf(bv, fmaxf(dn.x, dn.y));
      }
    }
    return;
  }

  // ======================= WORKERS (200 blocks) ==========================
  // Preamble: P1 = x @ W1[0:32] spread over all workers; block 4 also W2T.
  // P1 is large and cached: keep the ONE-TIME fence handshake (wb on
  // produce, inv on first consume) — its cost is once, not per center.
  {
    const int wbid = bid - BATCH;
    for (size_t e = (size_t)wbid * 1024 + tid; e < (size_t)32768 * 64;
         e += (size_t)NWORK * 1024) {
      const int j = (int)(e >> 6), c = (int)(e & 63);
      const float* __restrict__ xr = x + (size_t)j * DIN;
      float acc = 0.f;
#pragma unroll
      for (int k = 0; k < DIN; k++) acc += xr[k] * W1[k * 64 + c];
      P1[(size_t)j * 64 + c] = acc;
    }
    if (bid == BATCH) {
      for (int e = tid; e < 64 * 64; e += 1024) {
        const int c = e >> 6, k = e & 63;
        W2T[e] = W2[k * 64 + c];
      }
    }
    __syncthreads();                     // drains all threads' stores
    if (tid == 0) { __threadfence(); atomicAdd(p1done, 1); }
  }

  // Per-wave persistent loop: pull center tickets, spin until produced.
  unsigned long long* const cw =
      (unsigned long long*)smem + (size_t)wid * CAND_CAP;
  const float R2 = (float)(0.2 * 0.2);
  bool mlp_ready = false;

  for (;;) {
    int t;
    if (lane == 0) t = atomicAdd(ticket, 1);
    t = __builtin_amdgcn_readfirstlane(t);
    if (t >= BATCH * MP) break;
    const int b = t & 3;
    const int cIdx = t >> 2;             // ready-order: round-robin batches
    const int wg = b * MP + cIdx;

    while (aload(&prog[b]) < cIdx + 1) __builtin_amdgcn_s_sleep(32);
    // coords read uncached from the LLC — no fence needed (producer drained
    // its coord stores to the LLC before publishing prog).
    const float cx = afload(&pout[(size_t)wg * 3 + 0]);
    const float cy = afload(&pout[(size_t)wg * 3 + 1]);
    const float cz = afload(&pout[(size_t)wg * 3 + 2]);

    const float* __restrict__ pb = pos + (size_t)b * NP * 3;

    // ---- ball query: compaction (r7-verified) ----
    int cnt = 0;
    for (int basej = 0; basej < NP; basej += 64) {
      const int j = basej + lane;
      float dx = pb[j * 3 + 0] - cx;
      float dy = pb[j * 3 + 1] - cy;
      float dz = pb[j * 3 + 2] - cz;
      float d2 = dx * dx + dy * dy + dz * dz;
      bool in = (d2 <= R2);
      unsigned long long mb = __ballot(in);
      int pre = (int)__popcll(mb & ((1ull << lane) - 1ull));
      int slot = cnt + pre;
      if (in && slot < CAND_CAP)
        cw[slot] = ((unsigned long long)__float_as_uint(d2) << 32)
                   | (unsigned int)j;
      cnt += (int)__popcll(mb);
    }
    if (cnt > CAND_CAP) cnt = CAND_CAP;  // unreachable (max ~360)

    // ---- KNN selection: threshold scan + DPP argmin (r7-verified) ----
    unsigned long long last = 0;
    int myout = -1;
    for (int r = 0; r < KNN; r++) {
      unsigned long long v = ~0ull;
      for (int s = lane; s < cnt; s += 64) {
        const unsigned long long c = cw[s];
        if (c >= last && c < v) v = c;
      }
      const unsigned hi = (unsigned)(v >> 32);
      unsigned h = hi;
      DPP_WAVEMINU6(h);
      const unsigned mhi = (unsigned)__builtin_amdgcn_readlane((int)h, 63);
      const unsigned lo = (hi == mhi) ? (unsigned)v : 0xffffffffu;
      unsigned l2 = lo;
      DPP_WAVEMINU6(l2);
      const unsigned mlo = (unsigned)__builtin_amdgcn_readlane((int)l2, 63);
      if (lane == r) myout = (mhi == 0xffffffffu) ? -1 : (int)mlo;
      last = (mhi == 0xffffffffu)
                 ? ~0ull
                 : ((((unsigned long long)mhi << 32) | mlo) + 1ull);
    }

    if (!mlp_ready) {                    // P1/W2T ready gate (once per wave)
      while (aload(p1done) < NWORK) __builtin_amdgcn_s_sleep(32);
      __threadfence();                   // one-time L2 inv: P1/W2T fresh
      mlp_ready = true;
    }

    // ---- MLP + max (register-only, streaming h2; r8-verified math) ----
    const int idx = myout;
    const bool valid = idx >= 0;
    const int j = valid ? idx : 0;
    const float* __restrict__ pj = pos + ((size_t)b * NP + j) * 3;
    const float rx = pj[0] - cx, ry = pj[1] - cy, rz = pj[2] - cz;
    const float* __restrict__ p1r = (const float*)__builtin_assume_aligned(
        P1 + ((size_t)b * NP + j) * 64, 16);

    float h1[64];
#pragma unroll
    for (int k = 0; k < 64; k++) {
      float vv = p1r[k] + rx * W1[32 * 64 + k] + ry * W1[33 * 64 + k]
                        + rz * W1[34 * 64 + k] + b1[k];
      h1[k] = fmaxf(vv, 0.f);
    }

    float4 keep = make_float4(0.f, 0.f, 0.f, 0.f);
    for (int pass = 0; pass < 4; pass++) {
      float acc[32];
#pragma unroll
      for (int g = 0; g < 32; g++) acc[g] = b3[pass * 32 + g];
#pragma unroll 2
      for (int c = 0; c < 64; c++) {
        const float* __restrict__ w = W2T + c * 64;   // wave-uniform s_loads
        float a0 = 0.f, a1 = 0.f, a2 = 0.f, a3 = 0.f;
#pragma unroll
        for (int k4 = 0; k4 < 16; k4++) {
          a0 += h1[k4 * 4 + 0] * w[k4 * 4 + 0];
          a1 += h1[k4 * 4 + 1] * w[k4 * 4 + 1];
          a2 += h1[k4 * 4 + 2] * w[k4 * 4 + 2];
          a3 += h1[k4 * 4 + 3] * w[k4 * 4 + 3];
        }
        const float h2c = fmaxf(b2[c] + ((a0 + a1) + (a2 + a3)), 0.f);
        // W3 original [64][128]: row c, channel chunk pass*32..+32 contiguous
        const float* __restrict__ w3r = W3 + c * 128 + pass * 32;
#pragma unroll
        for (int g = 0; g < 32; g++) acc[g] += h2c * w3r[g];
      }
#pragma unroll
      for (int g4 = 0; g4 < 8; g4++) {
        float a0 = valid ? fmaxf(acc[g4 * 4 + 0], 0.f) : 0.f;
        float a1 = valid ? fmaxf(acc[g4 * 4 + 1], 0.f) : 0.f;
        float a2 = valid ? fmaxf(acc[g4 * 4 + 2], 0.f) : 0.f;
        float a3 = valid ? fmaxf(acc[g4 * 4 + 3], 0.f) : 0.f;
        DPP_WAVEMAX6(a0);
        DPP_WAVEMAX6(a1);
        DPP_WAVEMAX6(a2);
        DPP_WAVEMAX6(a3);
        const float m0 =
            __int_as_float(__builtin_amdgcn_readlane(__float_as_int(a0), 63));
        const float m1 =
            __int_as_float(__builtin_amdgcn_readlane(__float_as_int(a1), 63));
        const float m2 =
            __int_as_float(__builtin_amdgcn_readlane(__float_as_int(a2), 63));
        const float m3 =
            __int_as_float(__builtin_amdgcn_readlane(__float_as_int(a3), 63));
        if (lane == pass * 8 + g4) {
          keep.x = m0; keep.y = m1; keep.z = m2; keep.w = m3;
        }
      }
    }
    if (lane < 32)
      *(float4*)&xout[(size_t)wg * 128 + lane * 4] = keep;
  }
}

// --------------------------------------------------------------- launch ----
extern "C" void kernel_launch(void* const* d_in, const int* in_sizes, int n_in,
                              void* d_out, int out_size, void* d_ws, size_t ws_size,
                              hipStream_t stream)
{
  const float* x   = (const float*)d_in[0];
  const float* pos = (const float*)d_in[1];
  // d_in[2] = batch (unused; layout is implicit)
  const float* W1 = (const float*)d_in[3];
  const float* b1 = (const float*)d_in[4];
  const float* W2 = (const float*)d_in[5];
  const float* b2 = (const float*)d_in[6];
  const float* W3 = (const float*)d_in[7];
  const float* b3 = (const float*)d_in[8];

  float* out  = (float*)d_out;
  float* xout = out;                          // 8192*128
  float* pout = out + 8192 * 128;             // 8192*3
  float* bout = out + 8192 * 128 + 8192 * 3;  // 8192

  char* ws = (char*)d_ws;
  float* P1    = (float*)ws;
  float* W2T   = (float*)(ws + 8388608);
  int*   flags = (int*)(ws + 8404992);

  init_k<<<dim3(1), dim3(64), 0, stream>>>(flags);
  mega_k<<<dim3(NBLK), dim3(1024), 0, stream>>>(pos, x, W1, b1, W2, b2, W3,
                                                b3, pout, bout, P1, W2T,
                                                xout, flags);
}

// Round 10
// 2290.118 us; speedup vs baseline: 1.0687x; 1.0687x over previous
//
#include <hip/hip_runtime.h>

// PointNet++ SA module: FPS -> ball query (K nearest within R) -> gather ->
// 3-layer MLP -> masked max aggregation.
//
// B=4 batches, NP=8192 pts, MP=2048 centers/batch, K=64, R=0.2, D_IN=32.
// d_out = [x_out (8192*128) | pos_out (8192*3) | batch_out (8192)] as fp32.
//
// ws layout (bytes): flags only (256 ints, line-padded).
//
// Round-10: zero-shared-state overlap.  r9 proved the per-center fences were
// NOT the 61MB-fetch culprit; the remaining shared-state costs were P1 (8MB
// cross-XCD gather working set), per-wave threadfence P1-gates (3200 L2
// invalidates), and a poll storm on ONE cache line.  Fix: workers recompute
// x@W1 per center (~3.4us/center against ~15x idle capacity) => P1, W2T,
// p1done, and ALL fences deleted.  Only cross-block data: pout coords +
// prog flags, both relaxed agent-scope (uncached, LLC coherence point).
// Flags line-padded per batch; per-batch tickets (batch = worker bid & 3,
// XCD-affine => 1 batch of x/pos per L2); two-tier s_sleep poll backoff;
// NWORK 100 (slack ~8x).

#define BATCH 4
#define NP 8192
#define MP 2048
#define KNN 64
#define DIN 32
#define NWORK 100
#define NBLK (BATCH + NWORK)
#define CAND_CAP 512   // max real candidate count ~360 (measured r2-r9)

// One v_max_f32 + DPP step (r2-verified: plain fmaxf; asm variants regressed).
#define DPP_FMAX(v, ctrl)                                                     \
  {                                                                           \
    int _t = __builtin_amdgcn_update_dpp(__float_as_int(v),                   \
                                         __float_as_int(v), (ctrl), 0xF,      \
                                         0xF, false);                         \
    (v) = fmaxf((v), __int_as_float(_t));                                     \
  }

// One v_min_u32 + DPP step (integer: no canonicalization exists).
#define DPP_MINU(v, ctrl)                                                     \
  {                                                                           \
    unsigned _t = (unsigned)__builtin_amdgcn_update_dpp((int)(v), (int)(v),   \
                                                        (ctrl), 0xF, 0xF,    \
                                                        false);               \
    (v) = ((v) < _t) ? (v) : _t;                                              \
  }

#define DPP_WAVEMAX6(v)                                                       \
  {                                                                           \
    DPP_FMAX(v, 0x111); DPP_FMAX(v, 0x112); DPP_FMAX(v, 0x114);               \
    DPP_FMAX(v, 0x118); DPP_FMAX(v, 0x142); DPP_FMAX(v, 0x143);               \
  }

#define DPP_WAVEMINU6(v)                                                      \
  {                                                                           \
    DPP_MINU(v, 0x111); DPP_MINU(v, 0x112); DPP_MINU(v, 0x114);               \
    DPP_MINU(v, 0x118); DPP_MINU(v, 0x142); DPP_MINU(v, 0x143);               \
  }

typedef float v2f __attribute__((ext_vector_type(2)));

// Relaxed agent-scope atomics: bypass the non-coherent per-XCD L2s, served
// at the LLC coherence point.  NO fences attached (r9-verified handshake).
__device__ __forceinline__ int aload(const int* p) {
  return __hip_atomic_load(p, __ATOMIC_RELAXED, __HIP_MEMORY_SCOPE_AGENT);
}
__device__ __forceinline__ void astore_i(int* p, int v) {
  __hip_atomic_store(p, v, __ATOMIC_RELAXED, __HIP_MEMORY_SCOPE_AGENT);
}
__device__ __forceinline__ float afload(const float* p) {
  return __hip_atomic_load(p, __ATOMIC_RELAXED, __HIP_MEMORY_SCOPE_AGENT);
}
__device__ __forceinline__ void afstore(float* p, float v) {
  __hip_atomic_store(p, v, __ATOMIC_RELAXED, __HIP_MEMORY_SCOPE_AGENT);
}

// ---------------------------------------------------------------- init -----
__global__ void init_k(int* __restrict__ flags) {
  flags[threadIdx.x] = 0;   // 256 ints: prog[b*32], ticket[128+b*32]
}

// ---------------------------------------------------------------- mega -----
__global__ __launch_bounds__(1024) void mega_k(const float* __restrict__ pos,
                                               const float* __restrict__ x,
                                               const float* __restrict__ W1,
                                               const float* __restrict__ b1,
                                               const float* __restrict__ W2,
                                               const float* __restrict__ b2,
                                               const float* __restrict__ W3,
                                               const float* __restrict__ b3,
                                               float* __restrict__ pout,
                                               float* __restrict__ bout,
                                               float* __restrict__ xout,
                                               int* __restrict__ flags)
{
  // 98304B table (fps: ptab; workers: 16 x 512 u64 cand regions) + fps slots
  __shared__ __align__(16) float smem[NP * 3];
  __shared__ unsigned long long slt[2][16];

  const int bid = blockIdx.x;
  const int tid = threadIdx.x;
  const int lane = tid & 63, wid = tid >> 6;

  if (bid < BATCH) {
    // ===================== FPS (r2/r6-verified, 16 waves) =================
    const int b = bid;
    int* const prog = &flags[b * 32];        // one cache line per batch
    float* const ptab = smem;
    const float* __restrict__ pb = pos + (size_t)b * NP * 3;
    const int base = tid * 8;

    bout[b * MP + tid] = (float)b;
    bout[b * MP + 1024 + tid] = (float)b;

    // load 8 points; stage into LDS table; unpack to registers
    float t[24];
    const float4* __restrict__ pv = (const float4*)(pb + (size_t)tid * 24);
#pragma unroll
    for (int q = 0; q < 6; q++) *(float4*)&t[q * 4] = pv[q];
#pragma unroll
    for (int q = 0; q < 6; q++)
      *(float4*)&ptab[tid * 24 + q * 4] = *(float4*)&t[q * 4];

    v2f px[4], py[4], pz[4], d[4];
#pragma unroll
    for (int j = 0; j < 4; j++) {
      px[j].x = t[6 * j + 0]; py[j].x = t[6 * j + 1]; pz[j].x = t[6 * j + 2];
      px[j].y = t[6 * j + 3]; py[j].y = t[6 * j + 4]; pz[j].y = t[6 * j + 5];
    }

    const float c0x = pb[0], c0y = pb[1], c0z = pb[2];
    if (tid == 0) {  // sel[0] = 0   (uncached: workers read pout via LLC)
      afstore(&pout[(size_t)b * MP * 3 + 0], c0x);
      afstore(&pout[(size_t)b * MP * 3 + 1], c0y);
      afstore(&pout[(size_t)b * MP * 3 + 2], c0z);
    }

    float bv = -1.f;
    {
      v2f cx = {c0x, c0x}, cy = {c0y, c0y}, cz = {c0z, c0z};
#pragma unroll
      for (int j = 0; j < 4; j++) {
        v2f dx = px[j] - cx, dy = py[j] - cy, dz = pz[j] - cz;
        v2f nd = dx * dx + dy * dy + dz * dz;
        d[j] = nd;
        bv = fmaxf(bv, fmaxf(nd.x, nd.y));
      }
    }

    for (int i = 1; i < MP; i++) {
      float v = bv;
      DPP_WAVEMAX6(v);
      const float wmax =
          __int_as_float(__builtin_amdgcn_readlane(__float_as_int(v), 63));

      const unsigned long long m = __ballot(bv == wmax);
      const int src = (int)__builtin_ctzll(m);
      const int p = i & 1;
      if (lane == src) {
        int ks = 7;
#pragma unroll
        for (int k = 6; k >= 0; k--) {
          float dv = (k & 1) ? d[k >> 1].y : d[k >> 1].x;
          if (dv == wmax) ks = k;
        }
        slt[p][wid] = ((unsigned long long)__float_as_uint(wmax) << 32)
                      | (unsigned)(base + ks);
      }
      __syncthreads();

      const unsigned long long kv = slt[p][lane & 15];
      const float v2 = __uint_as_float((unsigned)(kv >> 32));
      float v2r = v2;
      DPP_FMAX(v2r, 0x111);
      DPP_FMAX(v2r, 0x112);
      DPP_FMAX(v2r, 0x114);
      DPP_FMAX(v2r, 0x118);
      const float mv =
          __int_as_float(__builtin_amdgcn_readlane(__float_as_int(v2r), 15));
      const unsigned long long m2 = __ballot(v2 == mv);
      const int mw = (int)__builtin_ctzll(m2);
      const int js = __builtin_amdgcn_readlane((int)(unsigned)kv, mw);
      const float ncx = ptab[js * 3 + 0];
      const float ncy = ptab[js * 3 + 1];
      const float ncz = ptab[js * 3 + 2];

      if (tid == 0) {
        // uncached coord stores: fire-and-forget to the LLC
        afstore(&pout[((size_t)b * MP + i) * 3 + 0], ncx);
        afstore(&pout[((size_t)b * MP + i) * 3 + 1], ncy);
        afstore(&pout[((size_t)b * MP + i) * 3 + 2], ncz);
        if ((i & 15) == 15) {
          // all prior coord stores reached the coherence point; publish.
          asm volatile("s_waitcnt vmcnt(0)" ::: "memory");
          astore_i(prog, i + 1);
        }
      }

      const v2f cx = {ncx, ncx}, cy = {ncy, ncy}, cz = {ncz, ncz};
      bv = -1.f;
#pragma unroll
      for (int j = 0; j < 4; j++) {
        v2f dx = px[j] - cx, dy = py[j] - cy, dz = pz[j] - cz;
        v2f nd = dx * dx + dy * dy + dz * dz;
        v2f dn;
        dn.x = fminf(d[j].x, nd.x);
        dn.y = fminf(d[j].y, nd.y);
        d[j] = dn;
        bv = fmaxf(bv, fmaxf(dn.x, dn.y));
      }
    }
    return;
  }

  // ======================= WORKERS (100 blocks) ==========================
  // batch = (bid-4) & 3: with round-robin block->XCD placement this gives
  // each XCD a single batch's x/pos working set (~1.1 MB << 4 MB L2).
  // NO fences anywhere: workers read only kernel inputs (pos, x, weights)
  // through the normal caches, plus pout/prog uncached.
  const int b = (bid - BATCH) & 3;
  int* const prog = &flags[b * 32];
  int* const tk   = &flags[128 + b * 32];
  unsigned long long* const cw =
      (unsigned long long*)smem + (size_t)wid * CAND_CAP;
  const float R2 = (float)(0.2 * 0.2);
  const float* __restrict__ pb = pos + (size_t)b * NP * 3;

  for (;;) {
    int t;
    if (lane == 0) t = atomicAdd(tk, 1);
    t = __builtin_amdgcn_readfirstlane(t);
    if (t >= MP) break;
    const int cIdx = t;
    const int wg = b * MP + cIdx;

    // poll with distance-aware backoff (worker knows how far ahead it is)
    int pr;
    while ((pr = aload(prog)) < cIdx + 1) {
      if (cIdx + 1 - pr > 64) __builtin_amdgcn_s_sleep(127);
      else                    __builtin_amdgcn_s_sleep(8);
    }
    // coords read uncached from the LLC — producer drained its coord
    // stores (vmcnt 0) before publishing prog.  No fence needed.
    const float cx = afload(&pout[(size_t)wg * 3 + 0]);
    const float cy = afload(&pout[(size_t)wg * 3 + 1]);
    const float cz = afload(&pout[(size_t)wg * 3 + 2]);

    // ---- ball query: compaction (r7-verified) ----
    int cnt = 0;
    for (int basej = 0; basej < NP; basej += 64) {
      const int j = basej + lane;
      float dx = pb[j * 3 + 0] - cx;
      float dy = pb[j * 3 + 1] - cy;
      float dz = pb[j * 3 + 2] - cz;
      float d2 = dx * dx + dy * dy + dz * dz;
      bool in = (d2 <= R2);
      unsigned long long mb = __ballot(in);
      int pre = (int)__popcll(mb & ((1ull << lane) - 1ull));
      int slot = cnt + pre;
      if (in && slot < CAND_CAP)
        cw[slot] = ((unsigned long long)__float_as_uint(d2) << 32)
                   | (unsigned int)j;
      cnt += (int)__popcll(mb);
    }
    if (cnt > CAND_CAP) cnt = CAND_CAP;  // unreachable (max ~360)

    // ---- KNN selection: threshold scan + DPP argmin (r7-verified) ----
    unsigned long long last = 0;
    int myout = -1;
    for (int r = 0; r < KNN; r++) {
      unsigned long long v = ~0ull;
      for (int s = lane; s < cnt; s += 64) {
        const unsigned long long c = cw[s];
        if (c >= last && c < v) v = c;
      }
      const unsigned hi = (unsigned)(v >> 32);
      unsigned h = hi;
      DPP_WAVEMINU6(h);
      const unsigned mhi = (unsigned)__builtin_amdgcn_readlane((int)h, 63);
      const unsigned lo = (hi == mhi) ? (unsigned)v : 0xffffffffu;
      unsigned l2 = lo;
      DPP_WAVEMINU6(l2);
      const unsigned mlo = (unsigned)__builtin_amdgcn_readlane((int)l2, 63);
      if (lane == r) myout = (mhi == 0xffffffffu) ? -1 : (int)mlo;
      last = (mhi == 0xffffffffu)
                 ? ~0ull
                 : ((((unsigned long long)mhi << 32) | mlo) + 1ull);
    }

    // ---- MLP + max: h1 recomputed from x (no P1), register-only ----
    const int idx = myout;
    const bool valid = idx >= 0;
    const int j = valid ? idx : 0;
    const float* __restrict__ pj = pos + ((size_t)b * NP + j) * 3;
    const float rx = pj[0] - cx, ry = pj[1] - cy, rz = pj[2] - cz;

    // x @ W1[0:32]: accumulate c ascending (identical chain to old p1_k),
    // W1 rows contiguous -> wide scalar loads.  x row gathered 128B/lane.
    float h1[64];
#pragma unroll
    for (int k = 0; k < 64; k++) h1[k] = 0.f;
    {
      const float* __restrict__ xr = x + ((size_t)b * NP + j) * DIN;
#pragma unroll
      for (int half = 0; half < 2; half++) {
        float xv[16];
#pragma unroll
        for (int q = 0; q < 4; q++)
          *(float4*)&xv[q * 4] = ((const float4*)xr)[half * 4 + q];
#pragma unroll
        for (int c = 0; c < 16; c++) {
          const float xc = xv[c];
          const float* __restrict__ w = W1 + (half * 16 + c) * 64;
#pragma unroll
          for (int k = 0; k < 64; k++) h1[k] += xc * w[k];
        }
      }
    }
#pragma unroll
    for (int k = 0; k < 64; k++) {
      float vv = h1[k] + rx * W1[32 * 64 + k] + ry * W1[33 * 64 + k]
                       + rz * W1[34 * 64 + k] + b1[k];
      h1[k] = fmaxf(vv, 0.f);
    }

    float4 keep = make_float4(0.f, 0.f, 0.f, 0.f);
    for (int pass = 0; pass < 4; pass++) {
      float acc[32];
#pragma unroll
      for (int g = 0; g < 32; g++) acc[g] = b3[pass * 32 + g];
#pragma unroll 2
      for (int c = 0; c < 64; c++) {
        // W2 column c (stride-64 wave-uniform s_loads; same values as the
        // old W2T rows — transpose buffer deleted)
        float a0 = 0.f, a1 = 0.f, a2 = 0.f, a3 = 0.f;
#pragma unroll
        for (int k4 = 0; k4 < 16; k4++) {
          a0 += h1[k4 * 4 + 0] * W2[(k4 * 4 + 0) * 64 + c];
          a1 += h1[k4 * 4 + 1] * W2[(k4 * 4 + 1) * 64 + c];
          a2 += h1[k4 * 4 + 2] * W2[(k4 * 4 + 2) * 64 + c];
          a3 += h1[k4 * 4 + 3] * W2[(k4 * 4 + 3) * 64 + c];
        }
        const float h2c = fmaxf(b2[c] + ((a0 + a1) + (a2 + a3)), 0.f);
        // W3 original [64][128]: row c, channel chunk pass*32..+32 contiguous
        const float* __restrict__ w3r = W3 + c * 128 + pass * 32;
#pragma unroll
        for (int g = 0; g < 32; g++) acc[g] += h2c * w3r[g];
      }
#pragma unroll
      for (int g4 = 0; g4 < 8; g4++) {
        float a0 = valid ? fmaxf(acc[g4 * 4 + 0], 0.f) : 0.f;
        float a1 = valid ? fmaxf(acc[g4 * 4 + 1], 0.f) : 0.f;
        float a2 = valid ? fmaxf(acc[g4 * 4 + 2], 0.f) : 0.f;
        float a3 = valid ? fmaxf(acc[g4 * 4 + 3], 0.f) : 0.f;
        DPP_WAVEMAX6(a0);
        DPP_WAVEMAX6(a1);
        DPP_WAVEMAX6(a2);
        DPP_WAVEMAX6(a3);
        const float m0 =
            __int_as_float(__builtin_amdgcn_readlane(__float_as_int(a0), 63));
        const float m1 =
            __int_as_float(__builtin_amdgcn_readlane(__float_as_int(a1), 63));
        const float m2 =
            __int_as_float(__builtin_amdgcn_readlane(__float_as_int(a2), 63));
        const float m3 =
            __int_as_float(__builtin_amdgcn_readlane(__float_as_int(a3), 63));
        if (lane == pass * 8 + g4) {
          keep.x = m0; keep.y = m1; keep.z = m2; keep.w = m3;
        }
      }
    }
    if (lane < 32)
      *(float4*)&xout[(size_t)wg * 128 + lane * 4] = keep;
  }
}

// --------------------------------------------------------------- launch ----
extern "C" void kernel_launch(void* const* d_in, const int* in_sizes, int n_in,
                              void* d_out, int out_size, void* d_ws, size_t ws_size,
                              hipStream_t stream)
{
  const float* x   = (const float*)d_in[0];
  const float* pos = (const float*)d_in[1];
  // d_in[2] = batch (unused; layout is implicit)
  const float* W1 = (const float*)d_in[3];
  const float* b1 = (const float*)d_in[4];
  const float* W2 = (const float*)d_in[5];
  const float* b2 = (const float*)d_in[6];
  const float* W3 = (const float*)d_in[7];
  const float* b3 = (const float*)d_in[8];

  float* out  = (float*)d_out;
  float* xout = out;                          // 8192*128
  float* pout = out + 8192 * 128;             // 8192*3
  float* bout = out + 8192 * 128 + 8192 * 3;  // 8192

  int* flags = (int*)d_ws;                    // 256 ints, line-padded

  init_k<<<dim3(1), dim3(256), 0, stream>>>(flags);
  mega_k<<<dim3(NBLK), dim3(1024), 0, stream>>>(pos, x, W1, b1, W2, b2, W3,
                                                b3, pout, bout, xout, flags);
}